// Round 6
// baseline (1212.564 us; speedup 1.0000x reference)
//
#include <hip/hip_runtime.h>
#include <hip/hip_bf16.h>
#include <cstdint>
#include <cstddef>

#define N_NODES 50000
#define N_EDGES 800000
#define G_GRAPHS 256
#define H_DIM 64
#define EPS_BN 1e-5f

// ---------------- degree count ----------------
__global__ void k_deg(const int* __restrict__ dst, int* __restrict__ cnt) {
    int e = blockIdx.x * 256 + threadIdx.x;
    if (e < N_EDGES) atomicAdd(&cnt[dst[e]], 1);
}

// ---------------- exclusive scan of counts (1 block) + dis = rsqrt(deg+1) ----------------
__global__ __launch_bounds__(1024) void k_scan_dis(const int* __restrict__ cnt,
                                                   int* __restrict__ row_ptr,
                                                   float* __restrict__ dis) {
    __shared__ int sh[1024];
    int t = threadIdx.x;
    int base = t * 49;
    int s = 0;
    for (int j = 0; j < 49; j++) {
        int i = base + j;
        if (i < N_NODES) {
            int c = cnt[i];
            dis[i] = rsqrtf((float)c + 1.0f);
            s += c;
        }
    }
    sh[t] = s;
    __syncthreads();
    for (int off = 1; off < 1024; off <<= 1) {
        int v = sh[t];
        int v2 = (t >= off) ? sh[t - off] : 0;
        __syncthreads();
        sh[t] = v + v2;
        __syncthreads();
    }
    int run = sh[t] - s;  // exclusive prefix of this thread's chunk
    for (int j = 0; j < 49; j++) {
        int i = base + j;
        if (i < N_NODES) { row_ptr[i] = run; run += cnt[i]; }
        else if (i == N_NODES) { row_ptr[i] = run; }
    }
}

// ---------------- CSR scatter ----------------
__global__ void k_scatter(const int* __restrict__ src, const int* __restrict__ dst,
                          const int* __restrict__ row_ptr, int* __restrict__ cursor,
                          int* __restrict__ csr) {
    int e = blockIdx.x * 256 + threadIdx.x;
    if (e < N_EDGES) {
        int d = dst[e];
        int p = atomicAdd(&cursor[d], 1);
        csr[row_ptr[d] + p] = src[e];
    }
}

// ---------------- input projection: h = x @ projW + b ----------------
__global__ void k_proj(const float* __restrict__ x, const float* __restrict__ W,
                       const float* __restrict__ b, float* __restrict__ h) {
    int tid = blockIdx.x * 256 + threadIdx.x;
    int i = tid >> 6, c = tid & 63;
    if (i < N_NODES) {
        float x0 = x[i * 3], x1 = x[i * 3 + 1], x2 = x[i * 3 + 2];
        h[tid] = x0 * W[c] + x1 * W[64 + c] + x2 * W[128 + c] + b[c];
    }
}

// ---------------- GEMM: out = f(in) @ W  * dis[i]  (f = id or BN+relu) ----------------
// MODE 0: f(v) = v.  MODE 1: f(v) = relu(v*a[c]+sh[c]).
template <int MODE>
__global__ __launch_bounds__(256) void k_gemm(const float* __restrict__ in,
                                              const float* __restrict__ Wg,
                                              const float* __restrict__ dis,
                                              const float* __restrict__ coef,
                                              float* __restrict__ out) {
    __shared__ float Wt[64 * 64];
    __shared__ float hT[64 * 65];
    __shared__ float sA[64], sSh[64];
    int t = threadIdx.x;
    int nb = blockIdx.x * 64;

    if (MODE == 1 && t < 64) { sA[t] = coef[t]; sSh[t] = coef[64 + t]; }
    __syncthreads();

    // stage W (64x64)
    const float4* W4 = (const float4*)Wg;
    float4* Wt4 = (float4*)Wt;
#pragma unroll
    for (int i = 0; i < 4; i++) Wt4[t + 256 * i] = W4[t + 256 * i];

    // stage h tile with transform, padded rows (65)
    int srow = t >> 4, c4 = t & 15;
#pragma unroll
    for (int i = 0; i < 4; i++) {
        int r = srow + 16 * i;
        int node = nb + r;
        float4 v = make_float4(0.f, 0.f, 0.f, 0.f);
        if (node < N_NODES) v = *(const float4*)&in[(size_t)node * 64 + c4 * 4];
        float e0 = v.x, e1 = v.y, e2 = v.z, e3 = v.w;
        if (MODE == 1) {
            int c = c4 * 4;
            e0 = fmaxf(e0 * sA[c] + sSh[c], 0.f);
            e1 = fmaxf(e1 * sA[c + 1] + sSh[c + 1], 0.f);
            e2 = fmaxf(e2 * sA[c + 2] + sSh[c + 2], 0.f);
            e3 = fmaxf(e3 * sA[c + 3] + sSh[c + 3], 0.f);
        }
        float* dr = &hT[r * 65 + c4 * 4];
        dr[0] = e0; dr[1] = e1; dr[2] = e2; dr[3] = e3;
    }
    __syncthreads();

    int c0 = (t & 15) * 4, n0 = (t >> 4) * 4;
    float acc[4][4];
#pragma unroll
    for (int j = 0; j < 4; j++)
#pragma unroll
        for (int i = 0; i < 4; i++) acc[j][i] = 0.f;

#pragma unroll 16
    for (int k = 0; k < 64; k++) {
        float4 wv = *(float4*)&Wt[k * 64 + c0];
        float h0 = hT[(n0 + 0) * 65 + k];
        float h1 = hT[(n0 + 1) * 65 + k];
        float h2 = hT[(n0 + 2) * 65 + k];
        float h3 = hT[(n0 + 3) * 65 + k];
        acc[0][0] += h0 * wv.x; acc[0][1] += h0 * wv.y; acc[0][2] += h0 * wv.z; acc[0][3] += h0 * wv.w;
        acc[1][0] += h1 * wv.x; acc[1][1] += h1 * wv.y; acc[1][2] += h1 * wv.z; acc[1][3] += h1 * wv.w;
        acc[2][0] += h2 * wv.x; acc[2][1] += h2 * wv.y; acc[2][2] += h2 * wv.z; acc[2][3] += h2 * wv.w;
        acc[3][0] += h3 * wv.x; acc[3][1] += h3 * wv.y; acc[3][2] += h3 * wv.z; acc[3][3] += h3 * wv.w;
    }

#pragma unroll
    for (int j = 0; j < 4; j++) {
        int node = nb + n0 + j;
        if (node < N_NODES) {
            float d = dis[node];
            float4 o;
            o.x = acc[j][0] * d; o.y = acc[j][1] * d; o.z = acc[j][2] * d; o.w = acc[j][3] * d;
            *(float4*)&out[(size_t)node * 64 + c0] = o;
        }
    }
}

// ---------------- aggregation: o[i] = dis[i]*(hwn[i] + sum_{j->i} hwn[j]); partial BN stats ----------------
__global__ __launch_bounds__(256) void k_agg(const float* __restrict__ hwn,
                                             const int* __restrict__ row_ptr,
                                             const int* __restrict__ csr,
                                             const float* __restrict__ dis,
                                             float* __restrict__ o,
                                             float* __restrict__ partial) {
    int t = threadIdx.x;
    int w = t >> 6, lane = t & 63;
    int gw = blockIdx.x * 4 + w;
    float sS = 0.f, sQ = 0.f;
    for (int i = gw; i < N_NODES; i += 4096) {
        float v = hwn[(size_t)i * 64 + lane];
        int beg = row_ptr[i], end = row_ptr[i + 1];
        int e = beg;
        for (; e + 4 <= end; e += 4) {
            int s0 = csr[e], s1 = csr[e + 1], s2 = csr[e + 2], s3 = csr[e + 3];
            float v0 = hwn[(size_t)s0 * 64 + lane];
            float v1 = hwn[(size_t)s1 * 64 + lane];
            float v2 = hwn[(size_t)s2 * 64 + lane];
            float v3 = hwn[(size_t)s3 * 64 + lane];
            v += (v0 + v1) + (v2 + v3);
        }
        for (; e < end; e++) v += hwn[(size_t)csr[e] * 64 + lane];
        v *= dis[i];
        o[(size_t)i * 64 + lane] = v;
        sS += v; sQ += v * v;
    }
    __shared__ float red[4][128];
    red[w][lane] = sS;
    red[w][64 + lane] = sQ;
    __syncthreads();
    if (t < 128) {
        float p = red[0][t] + red[1][t] + red[2][t] + red[3][t];
        partial[blockIdx.x * 128 + t] = p;
    }
}

// ---------------- finalize BN stats -> coef (a, shift) ----------------
__global__ __launch_bounds__(512) void k_fin(const float* __restrict__ partial,
                                             const float* __restrict__ g,
                                             const float* __restrict__ b,
                                             float* __restrict__ coef) {
    __shared__ float sh[4][128];
    __shared__ float st[128];
    int t = threadIdx.x;
    int c = t & 127, q = t >> 7;
    float acc = 0.f;
#pragma unroll 4
    for (int r = q; r < 1024; r += 4) acc += partial[r * 128 + c];
    sh[q][c] = acc;
    __syncthreads();
    if (t < 128) st[t] = sh[0][t] + sh[1][t] + sh[2][t] + sh[3][t];
    __syncthreads();
    if (t < 64) {
        float S = st[t], Q = st[t + 64];
        float mean = S * (1.0f / N_NODES);
        float var = Q * (1.0f / N_NODES) - mean * mean;
        float a = g[t] * rsqrtf(var + EPS_BN);
        coef[t] = a;
        coef[64 + t] = b[t] - mean * a;
    }
}

// ---------------- residual: hnew = relu(o2*a+sh + hold) ----------------
__global__ void k_res(const float* __restrict__ o2, const float* __restrict__ hold,
                      const float* __restrict__ coef, float* __restrict__ hnew) {
    int t4 = blockIdx.x * 256 + threadIdx.x;
    size_t base = (size_t)t4 * 4;
    int c0 = (int)(base & 63);
    float4 o = *(const float4*)&o2[base];
    float4 hi = *(const float4*)&hold[base];
    float4 r;
    r.x = fmaxf(o.x * coef[c0 + 0] + coef[64 + c0 + 0] + hi.x, 0.f);
    r.y = fmaxf(o.y * coef[c0 + 1] + coef[64 + c0 + 1] + hi.y, 0.f);
    r.z = fmaxf(o.z * coef[c0 + 2] + coef[64 + c0 + 2] + hi.z, 0.f);
    r.w = fmaxf(o.w * coef[c0 + 3] + coef[64 + c0 + 3] + hi.w, 0.f);
    *(float4*)&hnew[base] = r;
}

// ---------------- graph boundaries via binary search on sorted batch ----------------
__global__ void k_gbound(const int* __restrict__ batch, int* __restrict__ gstart) {
    int g = threadIdx.x;
    int lo = 0, hi = N_NODES;
    while (lo < hi) {
        int mid = (lo + hi) >> 1;
        if (batch[mid] < g) lo = mid + 1; else hi = mid;
    }
    gstart[g] = lo;
    if (g == 0) gstart[G_GRAPHS] = N_NODES;
}

// ---------------- per-graph mean/max pooling ----------------
__global__ __launch_bounds__(256) void k_pool(const float* __restrict__ h,
                                              const int* __restrict__ gstart,
                                              float* __restrict__ pmean,
                                              float* __restrict__ pmax) {
    int g = blockIdx.x;
    int s = gstart[g], e = gstart[g + 1];
    int t = threadIdx.x, w = t >> 6, lane = t & 63;
    float sum = 0.f, mx = 0.f;  // h >= 0 after relu; empty graph -> 0 matches guard
    for (int i = s + w; i < e; i += 4) {
        float v = h[(size_t)i * 64 + lane];
        sum += v;
        mx = fmaxf(mx, v);
    }
    __shared__ float rs[4][64], rm[4][64];
    rs[w][lane] = sum;
    rm[w][lane] = mx;
    __syncthreads();
    if (t < 64) {
        float S = rs[0][t] + rs[1][t] + rs[2][t] + rs[3][t];
        float M = fmaxf(fmaxf(rm[0][t], rm[1][t]), fmaxf(rm[2][t], rm[3][t]));
        float cntf = (float)(e - s);
        pmean[g * 64 + t] = S / fmaxf(cntf, 1.0f);
        pmax[g * 64 + t] = M;
    }
}

// ---------------- head: z=[mean||max]; 3 linears with 2 BN+relu, all in one block ----------------
__global__ __launch_bounds__(512) void k_head(const float* __restrict__ pmean,
                                              const float* __restrict__ pmax,
                                              const float* __restrict__ W1,
                                              const float* __restrict__ W2,
                                              const float* __restrict__ W3,
                                              const float* __restrict__ b3,
                                              const float* __restrict__ g1, const float* __restrict__ bb1,
                                              const float* __restrict__ g2, const float* __restrict__ bb2,
                                              float* __restrict__ ybuf, float* __restrict__ y2buf,
                                              float* __restrict__ outp) {
    int t = threadIdx.x;
    int w = t >> 6, lane = t & 63;
    int rgrp = w & 3, chalf = w >> 2;
    int r = rgrp * 64 + lane;
    __shared__ float pstat[8][32][2];
    __shared__ float aC[64], shC[64];

    // ---- Phase A: z1 = z @ W1 (z: [256,128]) ; this wave: rows rgrp*64+lane, cols chalf*32..+31
    float acc[32];
#pragma unroll
    for (int c = 0; c < 32; c++) acc[c] = 0.f;
    int c0 = chalf * 32;
    for (int kc = 0; kc < 4; kc++) {
        float zk[32];
#pragma unroll
        for (int j = 0; j < 32; j++) {
            int k = kc * 32 + j;
            zk[j] = (k < 64) ? pmean[r * 64 + k] : pmax[r * 64 + (k - 64)];
        }
        for (int j = 0; j < 32; j++) {
            float z = zk[j];
            int k = kc * 32 + j;
#pragma unroll
            for (int cq = 0; cq < 8; cq++) {
                float4 wv = *(const float4*)&W1[k * 64 + c0 + cq * 4];
                acc[cq * 4 + 0] += z * wv.x;
                acc[cq * 4 + 1] += z * wv.y;
                acc[cq * 4 + 2] += z * wv.z;
                acc[cq * 4 + 3] += z * wv.w;
            }
        }
    }
    // stats over 256 rows
    for (int c = 0; c < 32; c++) {
        float v = acc[c], q = acc[c] * acc[c];
        for (int m = 1; m < 64; m <<= 1) { v += __shfl_xor(v, m, 64); q += __shfl_xor(q, m, 64); }
        if (lane == 0) { pstat[w][c][0] = v; pstat[w][c][1] = q; }
    }
    __syncthreads();
    if (t < 64) {
        int ch = t >> 5, cc = t & 31;
        float S = 0.f, Q = 0.f;
        for (int i = 0; i < 4; i++) { S += pstat[ch * 4 + i][cc][0]; Q += pstat[ch * 4 + i][cc][1]; }
        float mean = S * (1.f / 256.f), var = Q * (1.f / 256.f) - mean * mean;
        float a = g1[t] * rsqrtf(var + EPS_BN);
        aC[t] = a;
        shC[t] = bb1[t] - mean * a;
    }
    __syncthreads();
    for (int c = 0; c < 32; c++) {
        float y = fmaxf(acc[c] * aC[c0 + c] + shC[c0 + c], 0.f);
        ybuf[r * 64 + c0 + c] = y;
    }
    __syncthreads();

    // ---- Phase B: z2 = y @ W2 ([256,64]@[64,32]); this wave: cols chalf*16..+15
    float acc2[16];
#pragma unroll
    for (int c = 0; c < 16; c++) acc2[c] = 0.f;
    int c0b = chalf * 16;
    for (int kc = 0; kc < 2; kc++) {
        float yk[32];
#pragma unroll
        for (int j = 0; j < 32; j++) yk[j] = ybuf[r * 64 + kc * 32 + j];
        for (int j = 0; j < 32; j++) {
            float y = yk[j];
            int k = kc * 32 + j;
#pragma unroll
            for (int cq = 0; cq < 4; cq++) {
                float4 wv = *(const float4*)&W2[k * 32 + c0b + cq * 4];
                acc2[cq * 4 + 0] += y * wv.x;
                acc2[cq * 4 + 1] += y * wv.y;
                acc2[cq * 4 + 2] += y * wv.z;
                acc2[cq * 4 + 3] += y * wv.w;
            }
        }
    }
    for (int c = 0; c < 16; c++) {
        float v = acc2[c], q = acc2[c] * acc2[c];
        for (int m = 1; m < 64; m <<= 1) { v += __shfl_xor(v, m, 64); q += __shfl_xor(q, m, 64); }
        if (lane == 0) { pstat[w][c][0] = v; pstat[w][c][1] = q; }
    }
    __syncthreads();
    if (t < 32) {
        int ch = t >> 4, cc = t & 15;
        float S = 0.f, Q = 0.f;
        for (int i = 0; i < 4; i++) { S += pstat[ch * 4 + i][cc][0]; Q += pstat[ch * 4 + i][cc][1]; }
        float mean = S * (1.f / 256.f), var = Q * (1.f / 256.f) - mean * mean;
        float a = g2[t] * rsqrtf(var + EPS_BN);
        aC[t] = a;
        shC[t] = bb2[t] - mean * a;
    }
    __syncthreads();
    for (int c = 0; c < 16; c++) {
        float y = fmaxf(acc2[c] * aC[c0b + c] + shC[c0b + c], 0.f);
        y2buf[r * 32 + c0b + c] = y;
    }
    __syncthreads();

    // ---- Phase C: out = y2 @ W3 + b3 ([256,32]@[32,2])
    if (chalf == 0) {
        float o0 = b3[0], o1 = b3[1];
        for (int j = 0; j < 32; j++) {
            float y = y2buf[r * 32 + j];
            o0 += y * W3[j * 2];
            o1 += y * W3[j * 2 + 1];
        }
        outp[r * 2] = o0;
        outp[r * 2 + 1] = o1;
    }
}

// ---------------- host ----------------
extern "C" void kernel_launch(void* const* d_in, const int* in_sizes, int n_in,
                              void* d_out, int out_size, void* d_ws, size_t ws_size,
                              hipStream_t stream) {
    (void)in_sizes; (void)n_in; (void)out_size; (void)ws_size;
    const float* x      = (const float*)d_in[0];
    const int*   ei     = (const int*)d_in[1];
    const int*   batch  = (const int*)d_in[2];
    const float* proj_W = (const float*)d_in[3];
    const float* proj_b = (const float*)d_in[4];
    const float* conv_W = (const float*)d_in[5];
    // d_in[6] conv_b: absorbed by BN
    const float* bn_g   = (const float*)d_in[7];
    const float* bn_b   = (const float*)d_in[8];
    const float* lin1_W = (const float*)d_in[9];
    // d_in[10] lin1_b absorbed
    const float* lin2_W = (const float*)d_in[11];
    // d_in[12] lin2_b absorbed
    const float* lin3_W = (const float*)d_in[13];
    const float* lin3_b = (const float*)d_in[14];
    const float* bnf1_g = (const float*)d_in[15];
    const float* bnf1_b = (const float*)d_in[16];
    const float* bnf2_g = (const float*)d_in[17];
    const float* bnf2_b = (const float*)d_in[18];
    const int* srcp = ei;
    const int* dstp = ei + N_EDGES;

    char* ws = (char*)d_ws;
    auto alloc = [&](size_t bytes) {
        char* p = ws;
        ws += (bytes + 255) / 256 * 256;
        return p;
    };
    int*   cnt     = (int*)alloc((size_t)N_NODES * 4);
    float* dis     = (float*)alloc((size_t)N_NODES * 4);
    int*   row_ptr = (int*)alloc((size_t)(N_NODES + 1) * 4);
    int*   cursor  = (int*)alloc((size_t)N_NODES * 4);
    int*   csr     = (int*)alloc((size_t)N_EDGES * 4);
    float* BA      = (float*)alloc((size_t)N_NODES * 64 * 4);
    float* BB      = (float*)alloc((size_t)N_NODES * 64 * 4);
    float* BC      = (float*)alloc((size_t)N_NODES * 64 * 4);
    float* partial = (float*)alloc((size_t)1024 * 128 * 4);
    float* coef    = (float*)alloc(128 * 4);
    float* pmean   = (float*)alloc((size_t)G_GRAPHS * 64 * 4);
    float* pmax    = (float*)alloc((size_t)G_GRAPHS * 64 * 4);
    int*   gstart  = (int*)alloc((size_t)(G_GRAPHS + 1) * 4);
    float* ybuf    = (float*)alloc((size_t)G_GRAPHS * 64 * 4);
    float* y2buf   = (float*)alloc((size_t)G_GRAPHS * 32 * 4);

    hipMemsetAsync(cnt, 0, (size_t)N_NODES * 4, stream);
    hipMemsetAsync(cursor, 0, (size_t)N_NODES * 4, stream);

    k_deg<<<3125, 256, 0, stream>>>(dstp, cnt);
    k_scan_dis<<<1, 1024, 0, stream>>>(cnt, row_ptr, dis);
    k_scatter<<<3125, 256, 0, stream>>>(srcp, dstp, row_ptr, cursor, csr);
    k_proj<<<12500, 256, 0, stream>>>(x, proj_W, proj_b, BA);

    // 3-buffer rotation: per layer A holds h_in.
    //   gemm A->B, agg B->C, gemm C->B, agg B->C, res(C,A)->B; then (A,B,C)<-(B,C,A).
    float* A = BA; float* B = BB; float* C = BC;
    for (int l = 0; l < 4; l++) {
        const float* W0 = conv_W + (size_t)(l * 2 + 0) * 4096;
        const float* W1c = conv_W + (size_t)(l * 2 + 1) * 4096;
        k_gemm<0><<<782, 256, 0, stream>>>(A, W0, dis, nullptr, B);
        k_agg<<<1024, 256, 0, stream>>>(B, row_ptr, csr, dis, C, partial);
        k_fin<<<1, 512, 0, stream>>>(partial, bn_g + (l * 2) * 64, bn_b + (l * 2) * 64, coef);
        k_gemm<1><<<782, 256, 0, stream>>>(C, W1c, dis, coef, B);
        k_agg<<<1024, 256, 0, stream>>>(B, row_ptr, csr, dis, C, partial);
        k_fin<<<1, 512, 0, stream>>>(partial, bn_g + (l * 2 + 1) * 64, bn_b + (l * 2 + 1) * 64, coef);
        k_res<<<3125, 256, 0, stream>>>(C, A, coef, B);
        float* t0 = A; A = B; B = C; C = t0;  // new h is in (old) B
    }

    k_gbound<<<1, 256, 0, stream>>>(batch, gstart);
    k_pool<<<256, 256, 0, stream>>>(A, gstart, pmean, pmax);
    k_head<<<1, 512, 0, stream>>>(pmean, pmax, lin1_W, lin2_W, lin3_W, lin3_b,
                                  bnf1_g, bnf1_b, bnf2_g, bnf2_b, ybuf, y2buf, (float*)d_out);
}

// Round 8
// 1143.541 us; speedup vs baseline: 1.0604x; 1.0604x over previous
//
#include <hip/hip_runtime.h>
#include <hip/hip_bf16.h>
#include <cstdint>
#include <cstddef>

#define N_NODES 50000
#define N_EDGES 800000
#define G_GRAPHS 256
#define H_DIM 64
#define EPS_BN 1e-5f

// ---------------- degree count ----------------
__global__ void k_deg(const int* __restrict__ dst, int* __restrict__ cnt) {
    int e = blockIdx.x * 256 + threadIdx.x;
    if (e < N_EDGES) atomicAdd(&cnt[dst[e]], 1);
}

// ---------------- exclusive scan of counts (1 block) + dis = rsqrt(deg+1) ----------------
__global__ __launch_bounds__(1024) void k_scan_dis(const int* __restrict__ cnt,
                                                   int* __restrict__ row_ptr,
                                                   float* __restrict__ dis) {
    __shared__ int sh[1024];
    int t = threadIdx.x;
    int base = t * 49;
    int s = 0;
    for (int j = 0; j < 49; j++) {
        int i = base + j;
        if (i < N_NODES) {
            int c = cnt[i];
            dis[i] = rsqrtf((float)c + 1.0f);
            s += c;
        }
    }
    sh[t] = s;
    __syncthreads();
    for (int off = 1; off < 1024; off <<= 1) {
        int v = sh[t];
        int v2 = (t >= off) ? sh[t - off] : 0;
        __syncthreads();
        sh[t] = v + v2;
        __syncthreads();
    }
    int run = sh[t] - s;  // exclusive prefix of this thread's chunk
    for (int j = 0; j < 49; j++) {
        int i = base + j;
        if (i < N_NODES) { row_ptr[i] = run; run += cnt[i]; }
        else if (i == N_NODES) { row_ptr[i] = run; }
    }
}

// ---------------- CSR scatter ----------------
__global__ void k_scatter(const int* __restrict__ src, const int* __restrict__ dst,
                          const int* __restrict__ row_ptr, int* __restrict__ cursor,
                          int* __restrict__ csr) {
    int e = blockIdx.x * 256 + threadIdx.x;
    if (e < N_EDGES) {
        int d = dst[e];
        int p = atomicAdd(&cursor[d], 1);
        csr[row_ptr[d] + p] = src[e];
    }
}

// ---------------- input projection: h = x @ projW + b ----------------
__global__ void k_proj(const float* __restrict__ x, const float* __restrict__ W,
                       const float* __restrict__ b, float* __restrict__ h) {
    int tid = blockIdx.x * 256 + threadIdx.x;
    int i = tid >> 6, c = tid & 63;
    if (i < N_NODES) {
        float x0 = x[i * 3], x1 = x[i * 3 + 1], x2 = x[i * 3 + 2];
        h[tid] = x0 * W[c] + x1 * W[64 + c] + x2 * W[128 + c] + b[c];
    }
}

// ---------------- GEMM: out = f(in) @ W  * dis[i]  (f = id or BN+relu) ----------------
template <int MODE>
__global__ __launch_bounds__(256) void k_gemm(const float* __restrict__ in,
                                              const float* __restrict__ Wg,
                                              const float* __restrict__ dis,
                                              const float* __restrict__ coef,
                                              float* __restrict__ out) {
    __shared__ float Wt[64 * 64];
    __shared__ float hT[64 * 65];
    __shared__ float sA[64], sSh[64];
    int t = threadIdx.x;
    int nb = blockIdx.x * 64;

    if (MODE == 1 && t < 64) { sA[t] = coef[t]; sSh[t] = coef[64 + t]; }
    __syncthreads();

    const float4* W4 = (const float4*)Wg;
    float4* Wt4 = (float4*)Wt;
#pragma unroll
    for (int i = 0; i < 4; i++) Wt4[t + 256 * i] = W4[t + 256 * i];

    int srow = t >> 4, c4 = t & 15;
#pragma unroll
    for (int i = 0; i < 4; i++) {
        int r = srow + 16 * i;
        int node = nb + r;
        float4 v = make_float4(0.f, 0.f, 0.f, 0.f);
        if (node < N_NODES) v = *(const float4*)&in[(size_t)node * 64 + c4 * 4];
        float e0 = v.x, e1 = v.y, e2 = v.z, e3 = v.w;
        if (MODE == 1) {
            int c = c4 * 4;
            e0 = fmaxf(e0 * sA[c] + sSh[c], 0.f);
            e1 = fmaxf(e1 * sA[c + 1] + sSh[c + 1], 0.f);
            e2 = fmaxf(e2 * sA[c + 2] + sSh[c + 2], 0.f);
            e3 = fmaxf(e3 * sA[c + 3] + sSh[c + 3], 0.f);
        }
        float* dr = &hT[r * 65 + c4 * 4];
        dr[0] = e0; dr[1] = e1; dr[2] = e2; dr[3] = e3;
    }
    __syncthreads();

    int c0 = (t & 15) * 4, n0 = (t >> 4) * 4;
    float acc[4][4];
#pragma unroll
    for (int j = 0; j < 4; j++)
#pragma unroll
        for (int i = 0; i < 4; i++) acc[j][i] = 0.f;

#pragma unroll 16
    for (int k = 0; k < 64; k++) {
        float4 wv = *(float4*)&Wt[k * 64 + c0];
        float h0 = hT[(n0 + 0) * 65 + k];
        float h1 = hT[(n0 + 1) * 65 + k];
        float h2 = hT[(n0 + 2) * 65 + k];
        float h3 = hT[(n0 + 3) * 65 + k];
        acc[0][0] += h0 * wv.x; acc[0][1] += h0 * wv.y; acc[0][2] += h0 * wv.z; acc[0][3] += h0 * wv.w;
        acc[1][0] += h1 * wv.x; acc[1][1] += h1 * wv.y; acc[1][2] += h1 * wv.z; acc[1][3] += h1 * wv.w;
        acc[2][0] += h2 * wv.x; acc[2][1] += h2 * wv.y; acc[2][2] += h2 * wv.z; acc[2][3] += h2 * wv.w;
        acc[3][0] += h3 * wv.x; acc[3][1] += h3 * wv.y; acc[3][2] += h3 * wv.z; acc[3][3] += h3 * wv.w;
    }

#pragma unroll
    for (int j = 0; j < 4; j++) {
        int node = nb + n0 + j;
        if (node < N_NODES) {
            float d = dis[node];
            float4 o;
            o.x = acc[j][0] * d; o.y = acc[j][1] * d; o.z = acc[j][2] * d; o.w = acc[j][3] * d;
            *(float4*)&out[(size_t)node * 64 + c0] = o;
        }
    }
}

// ---------------- aggregation: o[i] = dis[i]*(hwn[i] + sum_{j->i} hwn[j]); BN stats via atomics ----------------
__global__ __launch_bounds__(256) void k_agg(const float* __restrict__ hwn,
                                             const int* __restrict__ row_ptr,
                                             const int* __restrict__ csr,
                                             const float* __restrict__ dis,
                                             float* __restrict__ o,
                                             float* __restrict__ astat) {
    int t = threadIdx.x;
    int w = t >> 6, lane = t & 63;
    int gw = blockIdx.x * 4 + w;
    float sS = 0.f, sQ = 0.f;
    for (int i = gw; i < N_NODES; i += 8192) {
        float v = hwn[(size_t)i * 64 + lane];
        int beg = row_ptr[i], end = row_ptr[i + 1];
        int e = beg;
        for (; e + 4 <= end; e += 4) {
            int s0 = csr[e], s1 = csr[e + 1], s2 = csr[e + 2], s3 = csr[e + 3];
            float v0 = hwn[(size_t)s0 * 64 + lane];
            float v1 = hwn[(size_t)s1 * 64 + lane];
            float v2 = hwn[(size_t)s2 * 64 + lane];
            float v3 = hwn[(size_t)s3 * 64 + lane];
            v += (v0 + v1) + (v2 + v3);
        }
        for (; e < end; e++) v += hwn[(size_t)csr[e] * 64 + lane];
        v *= dis[i];
        o[(size_t)i * 64 + lane] = v;
        sS += v; sQ += v * v;
    }
    __shared__ float red[4][128];
    red[w][lane] = sS;
    red[w][64 + lane] = sQ;
    __syncthreads();
    if (t < 128) {
        float p = red[0][t] + red[1][t] + red[2][t] + red[3][t];
        atomicAdd(&astat[t], p);
    }
}

// ---------------- finalize BN stats -> coef (a, shift) ----------------
__global__ void k_fin(const float* __restrict__ astat,
                      const float* __restrict__ g,
                      const float* __restrict__ b,
                      float* __restrict__ coef) {
    int t = threadIdx.x;  // 64 threads
    float S = astat[t], Q = astat[64 + t];
    float mean = S * (1.0f / N_NODES);
    float var = Q * (1.0f / N_NODES) - mean * mean;
    float a = g[t] * rsqrtf(var + EPS_BN);
    coef[t] = a;
    coef[64 + t] = b[t] - mean * a;
}

// ---------------- residual: hnew = relu(o2*a+sh + hold) ----------------
__global__ void k_res(const float* __restrict__ o2, const float* __restrict__ hold,
                      const float* __restrict__ coef, float* __restrict__ hnew) {
    int t4 = blockIdx.x * 256 + threadIdx.x;
    size_t base = (size_t)t4 * 4;
    int c0 = (int)(base & 63);
    float4 o = *(const float4*)&o2[base];
    float4 hi = *(const float4*)&hold[base];
    float4 r;
    r.x = fmaxf(o.x * coef[c0 + 0] + coef[64 + c0 + 0] + hi.x, 0.f);
    r.y = fmaxf(o.y * coef[c0 + 1] + coef[64 + c0 + 1] + hi.y, 0.f);
    r.z = fmaxf(o.z * coef[c0 + 2] + coef[64 + c0 + 2] + hi.z, 0.f);
    r.w = fmaxf(o.w * coef[c0 + 3] + coef[64 + c0 + 3] + hi.w, 0.f);
    *(float4*)&hnew[base] = r;
}

// ---------------- per-graph mean/max pooling (bounds via inline binary search) ----------------
__global__ __launch_bounds__(256) void k_pool(const float* __restrict__ h,
                                              const int* __restrict__ batch,
                                              float* __restrict__ pmean,
                                              float* __restrict__ pmax) {
    int g = blockIdx.x;
    int lo = 0, hi = N_NODES;
    while (lo < hi) { int mid = (lo + hi) >> 1; if (batch[mid] < g) lo = mid + 1; else hi = mid; }
    int s = lo;
    hi = N_NODES;
    while (lo < hi) { int mid = (lo + hi) >> 1; if (batch[mid] < g + 1) lo = mid + 1; else hi = mid; }
    int e = lo;
    int t = threadIdx.x, w = t >> 6, lane = t & 63;
    float sum = 0.f, mx = 0.f;  // h >= 0 after relu
    for (int i = s + w; i < e; i += 4) {
        float v = h[(size_t)i * 64 + lane];
        sum += v;
        mx = fmaxf(mx, v);
    }
    __shared__ float rs[4][64], rm[4][64];
    rs[w][lane] = sum;
    rm[w][lane] = mx;
    __syncthreads();
    if (t < 64) {
        float S = rs[0][t] + rs[1][t] + rs[2][t] + rs[3][t];
        float M = fmaxf(fmaxf(rm[0][t], rm[1][t]), fmaxf(rm[2][t], rm[3][t]));
        float cntf = (float)(e - s);
        pmean[g * 64 + t] = S / fmaxf(cntf, 1.0f);
        pmax[g * 64 + t] = M;
    }
}

// ---------------- head stage 1: z1 = [mean||max] @ W1, stats -> hstat1 ----------------
// grid 32 x 256; block b: rows b*8..b*8+7; thread: row = b*8+(t>>5), 2 cols (t&31)*2
__global__ __launch_bounds__(256) void k_head1(const float* __restrict__ pmean,
                                               const float* __restrict__ pmax,
                                               const float* __restrict__ W1,
                                               float* __restrict__ z1,
                                               float* __restrict__ hstat1) {
    __shared__ float bs[128];
    int t = threadIdx.x;
    int row = blockIdx.x * 8 + (t >> 5);
    int col2 = (t & 31) * 2;
    if (t < 128) bs[t] = 0.f;
    __syncthreads();
    float acc0 = 0.f, acc1 = 0.f;
    const float* zr = &pmean[row * 64];
    for (int k = 0; k < 64; k++) {
        float zv = zr[k];
        float2 wv = *(const float2*)&W1[k * 64 + col2];
        acc0 += zv * wv.x; acc1 += zv * wv.y;
    }
    const float* zr2 = &pmax[row * 64];
    for (int k = 0; k < 64; k++) {
        float zv = zr2[k];
        float2 wv = *(const float2*)&W1[(64 + k) * 64 + col2];
        acc0 += zv * wv.x; acc1 += zv * wv.y;
    }
    *(float2*)&z1[row * 64 + col2] = make_float2(acc0, acc1);
    atomicAdd(&bs[col2], acc0);
    atomicAdd(&bs[col2 + 1], acc1);
    atomicAdd(&bs[64 + col2], acc0 * acc0);
    atomicAdd(&bs[64 + col2 + 1], acc1 * acc1);
    __syncthreads();
    if (t < 128) atomicAdd(&hstat1[t], bs[t]);
}

// ---------------- head stage 2: y = relu(bn1(z1)); z2 = y @ W2, stats -> hstat2 ----------------
__global__ __launch_bounds__(256) void k_head2(const float* __restrict__ z1,
                                               const float* __restrict__ W2,
                                               const float* __restrict__ hstat1,
                                               const float* __restrict__ g1,
                                               const float* __restrict__ bb1,
                                               float* __restrict__ z2,
                                               float* __restrict__ hstat2) {
    __shared__ float aC[64], shC[64], ys[8][64], bs2[64];
    int t = threadIdx.x;
    if (t < 64) {
        float S = hstat1[t], Q = hstat1[64 + t];
        float mean = S * (1.f / 256.f);
        float var = Q * (1.f / 256.f) - mean * mean;
        float a = g1[t] * rsqrtf(var + EPS_BN);
        aC[t] = a; shC[t] = bb1[t] - mean * a;
        bs2[t] = 0.f;
    }
    __syncthreads();
    for (int i = t; i < 512; i += 256) {
        int rl = i >> 6, k = i & 63;
        float v = z1[(blockIdx.x * 8 + rl) * 64 + k];
        ys[rl][k] = fmaxf(v * aC[k] + shC[k], 0.f);
    }
    __syncthreads();
    int rl = t >> 5, col = t & 31;
    float acc = 0.f;
    for (int k = 0; k < 64; k++) acc += ys[rl][k] * W2[k * 32 + col];
    z2[(blockIdx.x * 8 + rl) * 32 + col] = acc;
    atomicAdd(&bs2[col], acc);
    atomicAdd(&bs2[32 + col], acc * acc);
    __syncthreads();
    if (t < 64) atomicAdd(&hstat2[t], bs2[t]);
}

// ---------------- head stage 3: y2 = relu(bn2(z2)); out = y2 @ W3 + b3 ----------------
__global__ __launch_bounds__(256) void k_head3(const float* __restrict__ z2,
                                               const float* __restrict__ W3,
                                               const float* __restrict__ b3,
                                               const float* __restrict__ hstat2,
                                               const float* __restrict__ g2,
                                               const float* __restrict__ bb2,
                                               float* __restrict__ outp) {
    __shared__ float aC[32], shC[32];
    __shared__ float y2s[256 * 33];  // padded stride 33 to avoid bank conflicts
    int t = threadIdx.x;
    if (t < 32) {
        float S = hstat2[t], Q = hstat2[32 + t];
        float mean = S * (1.f / 256.f);
        float var = Q * (1.f / 256.f) - mean * mean;
        float a = g2[t] * rsqrtf(var + EPS_BN);
        aC[t] = a; shC[t] = bb2[t] - mean * a;
    }
    __syncthreads();
    for (int i = t; i < 8192; i += 256) {
        int r = i >> 5, k = i & 31;
        y2s[r * 33 + k] = fmaxf(z2[i] * aC[k] + shC[k], 0.f);
    }
    __syncthreads();
    float o0 = b3[0], o1 = b3[1];
    const float* yr = &y2s[t * 33];
    for (int k = 0; k < 32; k++) {
        float y = yr[k];
        o0 += y * W3[k * 2]; o1 += y * W3[k * 2 + 1];
    }
    outp[t * 2] = o0; outp[t * 2 + 1] = o1;
}

// ---------------- host ----------------
extern "C" void kernel_launch(void* const* d_in, const int* in_sizes, int n_in,
                              void* d_out, int out_size, void* d_ws, size_t ws_size,
                              hipStream_t stream) {
    (void)in_sizes; (void)n_in; (void)out_size; (void)ws_size;
    const float* x      = (const float*)d_in[0];
    const int*   ei     = (const int*)d_in[1];
    const int*   batch  = (const int*)d_in[2];
    const float* proj_W = (const float*)d_in[3];
    const float* proj_b = (const float*)d_in[4];
    const float* conv_W = (const float*)d_in[5];
    // d_in[6] conv_b absorbed by BN
    const float* bn_g   = (const float*)d_in[7];
    const float* bn_b   = (const float*)d_in[8];
    const float* lin1_W = (const float*)d_in[9];
    // d_in[10] lin1_b absorbed
    const float* lin2_W = (const float*)d_in[11];
    // d_in[12] lin2_b absorbed
    const float* lin3_W = (const float*)d_in[13];
    const float* lin3_b = (const float*)d_in[14];
    const float* bnf1_g = (const float*)d_in[15];
    const float* bnf1_b = (const float*)d_in[16];
    const float* bnf2_g = (const float*)d_in[17];
    const float* bnf2_b = (const float*)d_in[18];
    const int* srcp = ei;
    const int* dstp = ei + N_EDGES;

    char* ws = (char*)d_ws;
    auto alloc = [&](size_t bytes) {
        char* p = ws;
        ws += (bytes + 255) / 256 * 256;
        return p;
    };
    // zero-region first (one memset): cnt, cursor, stats
    int*   cnt     = (int*)alloc((size_t)N_NODES * 4);       // 200192 B padded
    int*   cursor  = (int*)alloc((size_t)N_NODES * 4);       // 200192 B padded
    float* stats   = (float*)alloc((size_t)1216 * 4);        // 8*128 astat + 128 hstat1 + 64 hstat2
    size_t zero_bytes = (size_t)ws - (size_t)d_ws;

    float* dis     = (float*)alloc((size_t)N_NODES * 4);
    int*   row_ptr = (int*)alloc((size_t)(N_NODES + 1) * 4);
    int*   csr     = (int*)alloc((size_t)N_EDGES * 4);
    float* BA      = (float*)alloc((size_t)N_NODES * 64 * 4);
    float* BB      = (float*)alloc((size_t)N_NODES * 64 * 4);
    float* BC      = (float*)alloc((size_t)N_NODES * 64 * 4);
    float* coef    = (float*)alloc(128 * 4);
    float* pmean   = (float*)alloc((size_t)G_GRAPHS * 64 * 4);
    float* pmax    = (float*)alloc((size_t)G_GRAPHS * 64 * 4);
    float* z1buf   = (float*)alloc((size_t)G_GRAPHS * 64 * 4);
    float* z2buf   = (float*)alloc((size_t)G_GRAPHS * 32 * 4);

    float* hstat1 = stats + 1024;
    float* hstat2 = stats + 1024 + 128;

    hipMemsetAsync(d_ws, 0, zero_bytes, stream);

    k_deg<<<3125, 256, 0, stream>>>(dstp, cnt);
    k_scan_dis<<<1, 1024, 0, stream>>>(cnt, row_ptr, dis);
    k_scatter<<<3125, 256, 0, stream>>>(srcp, dstp, row_ptr, cursor, csr);
    k_proj<<<12500, 256, 0, stream>>>(x, proj_W, proj_b, BA);

    // 3-buffer rotation: per layer A holds h_in.
    float* A = BA; float* B = BB; float* C = BC;
    for (int l = 0; l < 4; l++) {
        const float* W0 = conv_W + (size_t)(l * 2 + 0) * 4096;
        const float* W1c = conv_W + (size_t)(l * 2 + 1) * 4096;
        float* st0 = stats + (size_t)(l * 2 + 0) * 128;
        float* st1 = stats + (size_t)(l * 2 + 1) * 128;
        k_gemm<0><<<782, 256, 0, stream>>>(A, W0, dis, nullptr, B);
        k_agg<<<2048, 256, 0, stream>>>(B, row_ptr, csr, dis, C, st0);
        k_fin<<<1, 64, 0, stream>>>(st0, bn_g + (l * 2) * 64, bn_b + (l * 2) * 64, coef);
        k_gemm<1><<<782, 256, 0, stream>>>(C, W1c, dis, coef, B);
        k_agg<<<2048, 256, 0, stream>>>(B, row_ptr, csr, dis, C, st1);
        k_fin<<<1, 64, 0, stream>>>(st1, bn_g + (l * 2 + 1) * 64, bn_b + (l * 2 + 1) * 64, coef);
        k_res<<<3125, 256, 0, stream>>>(C, A, coef, B);
        float* t0 = A; A = B; B = C; C = t0;  // new h in (old) B
    }

    k_pool<<<256, 256, 0, stream>>>(A, batch, pmean, pmax);
    k_head1<<<32, 256, 0, stream>>>(pmean, pmax, lin1_W, z1buf, hstat1);
    k_head2<<<32, 256, 0, stream>>>(z1buf, lin2_W, hstat1, bnf1_g, bnf1_b, z2buf, hstat2);
    k_head3<<<1, 256, 0, stream>>>(z2buf, lin3_W, lin3_b, hstat2, bnf2_g, bnf2_b, (float*)d_out);
}

// Round 14
// 1018.508 us; speedup vs baseline: 1.1905x; 1.1228x over previous
//
#include <hip/hip_runtime.h>
#include <hip/hip_bf16.h>
#include <cstdint>
#include <cstddef>

#define N_NODES 50000
#define N_EDGES 800000
#define G_GRAPHS 256
#define H_DIM 64
#define EPS_BN 1e-5f
#define NB_SCAN 196  // ceil(50000/256)

// ---------------- degree count ----------------
__global__ void k_deg(const int* __restrict__ dst, int* __restrict__ cnt) {
    int e = blockIdx.x * 256 + threadIdx.x;
    if (e < N_EDGES) atomicAdd(&cnt[dst[e]], 1);
}

// ---------------- hierarchical scan stage 1: block sums + dis ----------------
__global__ __launch_bounds__(256) void k_bsum(const int* __restrict__ cnt,
                                              int* __restrict__ bsum,
                                              float* __restrict__ dis) {
    __shared__ int sh[256];
    int t = threadIdx.x;
    int i = blockIdx.x * 256 + t;
    int c = (i < N_NODES) ? cnt[i] : 0;
    if (i < N_NODES) dis[i] = rsqrtf((float)c + 1.0f);
    sh[t] = c;
    __syncthreads();
    for (int off = 128; off > 0; off >>= 1) {
        if (t < off) sh[t] += sh[t + off];
        __syncthreads();
    }
    if (t == 0) bsum[blockIdx.x] = sh[0];
}

// ---------------- hierarchical scan stage 2: scan of block sums (1 block) ----------------
__global__ __launch_bounds__(256) void k_bscan(const int* __restrict__ bsum,
                                               int* __restrict__ boff,
                                               int* __restrict__ row_ptr) {
    __shared__ int sh[256];
    int t = threadIdx.x;
    int v = (t < NB_SCAN) ? bsum[t] : 0;
    sh[t] = v;
    __syncthreads();
    for (int off = 1; off < 256; off <<= 1) {
        int add = (t >= off) ? sh[t - off] : 0;
        __syncthreads();
        sh[t] += add;
        __syncthreads();
    }
    if (t < NB_SCAN) boff[t] = sh[t] - v;  // exclusive
    if (t == 0) row_ptr[N_NODES] = N_EDGES;
}

// ---------------- hierarchical scan stage 3: row_ptr = boff[b] + intra-block exclusive scan ----------------
__global__ __launch_bounds__(256) void k_rowptr(const int* __restrict__ cnt,
                                                const int* __restrict__ boff,
                                                int* __restrict__ row_ptr) {
    __shared__ int sh[256];
    int t = threadIdx.x;
    int i = blockIdx.x * 256 + t;
    int c = (i < N_NODES) ? cnt[i] : 0;
    sh[t] = c;
    __syncthreads();
    for (int off = 1; off < 256; off <<= 1) {
        int add = (t >= off) ? sh[t - off] : 0;
        __syncthreads();
        sh[t] += add;
        __syncthreads();
    }
    if (i < N_NODES) row_ptr[i] = boff[blockIdx.x] + sh[t] - c;
}

// ---------------- CSR scatter ----------------
__global__ void k_scatter(const int* __restrict__ src, const int* __restrict__ dst,
                          const int* __restrict__ row_ptr, int* __restrict__ cursor,
                          int* __restrict__ csr) {
    int e = blockIdx.x * 256 + threadIdx.x;
    if (e < N_EDGES) {
        int d = dst[e];
        int p = atomicAdd(&cursor[d], 1);
        csr[row_ptr[d] + p] = src[e];
    }
}

// ---------------- input projection: h = x @ projW + b ----------------
__global__ void k_proj(const float* __restrict__ x, const float* __restrict__ W,
                       const float* __restrict__ b, float* __restrict__ h) {
    int tid = blockIdx.x * 256 + threadIdx.x;
    int i = tid >> 6, c = tid & 63;
    if (i < N_NODES) {
        float x0 = x[i * 3], x1 = x[i * 3 + 1], x2 = x[i * 3 + 2];
        h[tid] = x0 * W[c] + x1 * W[64 + c] + x2 * W[128 + c] + b[c];
    }
}

// ---------------- GEMM: out = f(in) @ W  * dis[i]  (f = id or BN+relu) ----------------
template <int MODE>
__global__ __launch_bounds__(256) void k_gemm(const float* __restrict__ in,
                                              const float* __restrict__ Wg,
                                              const float* __restrict__ dis,
                                              const float* __restrict__ coef,
                                              float* __restrict__ out) {
    __shared__ float Wt[64 * 64];
    __shared__ float hT[64 * 65];
    __shared__ float sA[64], sSh[64];
    int t = threadIdx.x;
    int nb = blockIdx.x * 64;

    if (MODE == 1 && t < 64) { sA[t] = coef[t]; sSh[t] = coef[64 + t]; }
    __syncthreads();

    const float4* W4 = (const float4*)Wg;
    float4* Wt4 = (float4*)Wt;
#pragma unroll
    for (int i = 0; i < 4; i++) Wt4[t + 256 * i] = W4[t + 256 * i];

    int srow = t >> 4, c4 = t & 15;
#pragma unroll
    for (int i = 0; i < 4; i++) {
        int r = srow + 16 * i;
        int node = nb + r;
        float4 v = make_float4(0.f, 0.f, 0.f, 0.f);
        if (node < N_NODES) v = *(const float4*)&in[(size_t)node * 64 + c4 * 4];
        float e0 = v.x, e1 = v.y, e2 = v.z, e3 = v.w;
        if (MODE == 1) {
            int c = c4 * 4;
            e0 = fmaxf(e0 * sA[c] + sSh[c], 0.f);
            e1 = fmaxf(e1 * sA[c + 1] + sSh[c + 1], 0.f);
            e2 = fmaxf(e2 * sA[c + 2] + sSh[c + 2], 0.f);
            e3 = fmaxf(e3 * sA[c + 3] + sSh[c + 3], 0.f);
        }
        float* dr = &hT[r * 65 + c4 * 4];
        dr[0] = e0; dr[1] = e1; dr[2] = e2; dr[3] = e3;
    }
    __syncthreads();

    int c0 = (t & 15) * 4, n0 = (t >> 4) * 4;
    float acc[4][4];
#pragma unroll
    for (int j = 0; j < 4; j++)
#pragma unroll
        for (int i = 0; i < 4; i++) acc[j][i] = 0.f;

#pragma unroll 16
    for (int k = 0; k < 64; k++) {
        float4 wv = *(float4*)&Wt[k * 64 + c0];
        float h0 = hT[(n0 + 0) * 65 + k];
        float h1 = hT[(n0 + 1) * 65 + k];
        float h2 = hT[(n0 + 2) * 65 + k];
        float h3 = hT[(n0 + 3) * 65 + k];
        acc[0][0] += h0 * wv.x; acc[0][1] += h0 * wv.y; acc[0][2] += h0 * wv.z; acc[0][3] += h0 * wv.w;
        acc[1][0] += h1 * wv.x; acc[1][1] += h1 * wv.y; acc[1][2] += h1 * wv.z; acc[1][3] += h1 * wv.w;
        acc[2][0] += h2 * wv.x; acc[2][1] += h2 * wv.y; acc[2][2] += h2 * wv.z; acc[2][3] += h2 * wv.w;
        acc[3][0] += h3 * wv.x; acc[3][1] += h3 * wv.y; acc[3][2] += h3 * wv.z; acc[3][3] += h3 * wv.w;
    }

#pragma unroll
    for (int j = 0; j < 4; j++) {
        int node = nb + n0 + j;
        if (node < N_NODES) {
            float d = dis[node];
            float4 o;
            o.x = acc[j][0] * d; o.y = acc[j][1] * d; o.z = acc[j][2] * d; o.w = acc[j][3] * d;
            *(float4*)&out[(size_t)node * 64 + c0] = o;
        }
    }
}

// ---------------- aggregation: o[i] = dis[i]*(hwn[i] + sum_{j->i} hwn[j]); BN stats via atomics ----------------
__global__ __launch_bounds__(256) void k_agg(const float* __restrict__ hwn,
                                             const int* __restrict__ row_ptr,
                                             const int* __restrict__ csr,
                                             const float* __restrict__ dis,
                                             float* __restrict__ o,
                                             float* __restrict__ astat) {
    int t = threadIdx.x;
    int w = t >> 6, lane = t & 63;
    int gw = blockIdx.x * 4 + w;
    float sS = 0.f, sQ = 0.f;
    for (int i = gw; i < N_NODES; i += 8192) {
        float v = hwn[(size_t)i * 64 + lane];
        int beg = row_ptr[i], end = row_ptr[i + 1];
        int e = beg;
        for (; e + 4 <= end; e += 4) {
            int s0 = csr[e], s1 = csr[e + 1], s2 = csr[e + 2], s3 = csr[e + 3];
            float v0 = hwn[(size_t)s0 * 64 + lane];
            float v1 = hwn[(size_t)s1 * 64 + lane];
            float v2 = hwn[(size_t)s2 * 64 + lane];
            float v3 = hwn[(size_t)s3 * 64 + lane];
            v += (v0 + v1) + (v2 + v3);
        }
        for (; e < end; e++) v += hwn[(size_t)csr[e] * 64 + lane];
        v *= dis[i];
        o[(size_t)i * 64 + lane] = v;
        sS += v; sQ += v * v;
    }
    __shared__ float red[4][128];
    red[w][lane] = sS;
    red[w][64 + lane] = sQ;
    __syncthreads();
    if (t < 128) {
        float p = red[0][t] + red[1][t] + red[2][t] + red[3][t];
        atomicAdd(&astat[t], p);
    }
}

// ---------------- finalize BN stats -> coef (a, shift) ----------------
__global__ void k_fin(const float* __restrict__ astat,
                      const float* __restrict__ g,
                      const float* __restrict__ b,
                      float* __restrict__ coef) {
    int t = threadIdx.x;  // 64 threads
    float S = astat[t], Q = astat[64 + t];
    float mean = S * (1.0f / N_NODES);
    float var = Q * (1.0f / N_NODES) - mean * mean;
    float a = g[t] * rsqrtf(var + EPS_BN);
    coef[t] = a;
    coef[64 + t] = b[t] - mean * a;
}

// ---------------- residual: hnew = relu(o2*a+sh + hold) ----------------
__global__ void k_res(const float* __restrict__ o2, const float* __restrict__ hold,
                      const float* __restrict__ coef, float* __restrict__ hnew) {
    int t4 = blockIdx.x * 256 + threadIdx.x;
    size_t base = (size_t)t4 * 4;
    int c0 = (int)(base & 63);
    float4 o = *(const float4*)&o2[base];
    float4 hi = *(const float4*)&hold[base];
    float4 r;
    r.x = fmaxf(o.x * coef[c0 + 0] + coef[64 + c0 + 0] + hi.x, 0.f);
    r.y = fmaxf(o.y * coef[c0 + 1] + coef[64 + c0 + 1] + hi.y, 0.f);
    r.z = fmaxf(o.z * coef[c0 + 2] + coef[64 + c0 + 2] + hi.z, 0.f);
    r.w = fmaxf(o.w * coef[c0 + 3] + coef[64 + c0 + 3] + hi.w, 0.f);
    *(float4*)&hnew[base] = r;
}

// ---------------- per-graph mean/max pooling (bounds via inline binary search) ----------------
__global__ __launch_bounds__(256) void k_pool(const float* __restrict__ h,
                                              const int* __restrict__ batch,
                                              float* __restrict__ pmean,
                                              float* __restrict__ pmax) {
    int g = blockIdx.x;
    int lo = 0, hi = N_NODES;
    while (lo < hi) { int mid = (lo + hi) >> 1; if (batch[mid] < g) lo = mid + 1; else hi = mid; }
    int s = lo;
    hi = N_NODES;
    while (lo < hi) { int mid = (lo + hi) >> 1; if (batch[mid] < g + 1) lo = mid + 1; else hi = mid; }
    int e = lo;
    int t = threadIdx.x, w = t >> 6, lane = t & 63;
    float sum = 0.f, mx = 0.f;  // h >= 0 after relu
    for (int i = s + w; i < e; i += 4) {
        float v = h[(size_t)i * 64 + lane];
        sum += v;
        mx = fmaxf(mx, v);
    }
    __shared__ float rs[4][64], rm[4][64];
    rs[w][lane] = sum;
    rm[w][lane] = mx;
    __syncthreads();
    if (t < 64) {
        float S = rs[0][t] + rs[1][t] + rs[2][t] + rs[3][t];
        float M = fmaxf(fmaxf(rm[0][t], rm[1][t]), fmaxf(rm[2][t], rm[3][t]));
        float cntf = (float)(e - s);
        pmean[g * 64 + t] = S / fmaxf(cntf, 1.0f);
        pmax[g * 64 + t] = M;
    }
}

// ---------------- head stage 1: z1 = [mean||max] @ W1, stats -> hstat1 ----------------
__global__ __launch_bounds__(256) void k_head1(const float* __restrict__ pmean,
                                               const float* __restrict__ pmax,
                                               const float* __restrict__ W1,
                                               float* __restrict__ z1,
                                               float* __restrict__ hstat1) {
    __shared__ float bs[128];
    int t = threadIdx.x;
    int row = blockIdx.x * 8 + (t >> 5);
    int col2 = (t & 31) * 2;
    if (t < 128) bs[t] = 0.f;
    __syncthreads();
    float acc0 = 0.f, acc1 = 0.f;
    const float* zr = &pmean[row * 64];
    for (int k = 0; k < 64; k++) {
        float zv = zr[k];
        float2 wv = *(const float2*)&W1[k * 64 + col2];
        acc0 += zv * wv.x; acc1 += zv * wv.y;
    }
    const float* zr2 = &pmax[row * 64];
    for (int k = 0; k < 64; k++) {
        float zv = zr2[k];
        float2 wv = *(const float2*)&W1[(64 + k) * 64 + col2];
        acc0 += zv * wv.x; acc1 += zv * wv.y;
    }
    *(float2*)&z1[row * 64 + col2] = make_float2(acc0, acc1);
    atomicAdd(&bs[col2], acc0);
    atomicAdd(&bs[col2 + 1], acc1);
    atomicAdd(&bs[64 + col2], acc0 * acc0);
    atomicAdd(&bs[64 + col2 + 1], acc1 * acc1);
    __syncthreads();
    if (t < 128) atomicAdd(&hstat1[t], bs[t]);
}

// ---------------- head stage 2: y = relu(bn1(z1)); z2 = y @ W2, stats -> hstat2 ----------------
__global__ __launch_bounds__(256) void k_head2(const float* __restrict__ z1,
                                               const float* __restrict__ W2,
                                               const float* __restrict__ hstat1,
                                               const float* __restrict__ g1,
                                               const float* __restrict__ bb1,
                                               float* __restrict__ z2,
                                               float* __restrict__ hstat2) {
    __shared__ float aC[64], shC[64], ys[8][64], bs2[64];
    int t = threadIdx.x;
    if (t < 64) {
        float S = hstat1[t], Q = hstat1[64 + t];
        float mean = S * (1.f / 256.f);
        float var = Q * (1.f / 256.f) - mean * mean;
        float a = g1[t] * rsqrtf(var + EPS_BN);
        aC[t] = a; shC[t] = bb1[t] - mean * a;
        bs2[t] = 0.f;
    }
    __syncthreads();
    for (int i = t; i < 512; i += 256) {
        int rl = i >> 6, k = i & 63;
        float v = z1[(blockIdx.x * 8 + rl) * 64 + k];
        ys[rl][k] = fmaxf(v * aC[k] + shC[k], 0.f);
    }
    __syncthreads();
    int rl = t >> 5, col = t & 31;
    float acc = 0.f;
    for (int k = 0; k < 64; k++) acc += ys[rl][k] * W2[k * 32 + col];
    z2[(blockIdx.x * 8 + rl) * 32 + col] = acc;
    atomicAdd(&bs2[col], acc);
    atomicAdd(&bs2[32 + col], acc * acc);
    __syncthreads();
    if (t < 64) atomicAdd(&hstat2[t], bs2[t]);
}

// ---------------- head stage 3: y2 = relu(bn2(z2)); out = y2 @ W3 + b3 ----------------
__global__ __launch_bounds__(256) void k_head3(const float* __restrict__ z2,
                                               const float* __restrict__ W3,
                                               const float* __restrict__ b3,
                                               const float* __restrict__ hstat2,
                                               const float* __restrict__ g2,
                                               const float* __restrict__ bb2,
                                               float* __restrict__ outp) {
    __shared__ float aC[32], shC[32];
    __shared__ float y2s[256 * 33];  // padded stride 33
    int t = threadIdx.x;
    if (t < 32) {
        float S = hstat2[t], Q = hstat2[32 + t];
        float mean = S * (1.f / 256.f);
        float var = Q * (1.f / 256.f) - mean * mean;
        float a = g2[t] * rsqrtf(var + EPS_BN);
        aC[t] = a; shC[t] = bb2[t] - mean * a;
    }
    __syncthreads();
    for (int i = t; i < 8192; i += 256) {
        int r = i >> 5, k = i & 31;
        y2s[r * 33 + k] = fmaxf(z2[i] * aC[k] + shC[k], 0.f);
    }
    __syncthreads();
    float o0 = b3[0], o1 = b3[1];
    const float* yr = &y2s[t * 33];
    for (int k = 0; k < 32; k++) {
        float y = yr[k];
        o0 += y * W3[k * 2]; o1 += y * W3[k * 2 + 1];
    }
    outp[t * 2] = o0; outp[t * 2 + 1] = o1;
}

// ---------------- host ----------------
extern "C" void kernel_launch(void* const* d_in, const int* in_sizes, int n_in,
                              void* d_out, int out_size, void* d_ws, size_t ws_size,
                              hipStream_t stream) {
    (void)in_sizes; (void)n_in; (void)out_size; (void)ws_size;
    const float* x      = (const float*)d_in[0];
    const int*   ei     = (const int*)d_in[1];
    const int*   batch  = (const int*)d_in[2];
    const float* proj_W = (const float*)d_in[3];
    const float* proj_b = (const float*)d_in[4];
    const float* conv_W = (const float*)d_in[5];
    // d_in[6] conv_b absorbed by BN
    const float* bn_g   = (const float*)d_in[7];
    const float* bn_b   = (const float*)d_in[8];
    const float* lin1_W = (const float*)d_in[9];
    // d_in[10] lin1_b absorbed
    const float* lin2_W = (const float*)d_in[11];
    // d_in[12] lin2_b absorbed
    const float* lin3_W = (const float*)d_in[13];
    const float* lin3_b = (const float*)d_in[14];
    const float* bnf1_g = (const float*)d_in[15];
    const float* bnf1_b = (const float*)d_in[16];
    const float* bnf2_g = (const float*)d_in[17];
    const float* bnf2_b = (const float*)d_in[18];
    const int* srcp = ei;
    const int* dstp = ei + N_EDGES;

    char* ws = (char*)d_ws;
    auto alloc = [&](size_t bytes) {
        char* p = ws;
        ws += (bytes + 255) / 256 * 256;
        return p;
    };
    // zero-region first (one memset): cnt, cursor, stats
    int*   cnt     = (int*)alloc((size_t)N_NODES * 4);
    int*   cursor  = (int*)alloc((size_t)N_NODES * 4);
    float* stats   = (float*)alloc((size_t)1216 * 4);  // 8*128 astat + 128 hstat1 + 64 hstat2
    size_t zero_bytes = (size_t)ws - (size_t)d_ws;

    float* dis     = (float*)alloc((size_t)N_NODES * 4);
    int*   row_ptr = (int*)alloc((size_t)(N_NODES + 1) * 4);
    int*   csr     = (int*)alloc((size_t)N_EDGES * 4);
    int*   bsum    = (int*)alloc((size_t)NB_SCAN * 4);
    int*   boff    = (int*)alloc((size_t)NB_SCAN * 4);
    float* BA      = (float*)alloc((size_t)N_NODES * 64 * 4);
    float* BB      = (float*)alloc((size_t)N_NODES * 64 * 4);
    float* BC      = (float*)alloc((size_t)N_NODES * 64 * 4);
    float* coef    = (float*)alloc(128 * 4);
    float* pmean   = (float*)alloc((size_t)G_GRAPHS * 64 * 4);
    float* pmax    = (float*)alloc((size_t)G_GRAPHS * 64 * 4);
    float* z1buf   = (float*)alloc((size_t)G_GRAPHS * 64 * 4);
    float* z2buf   = (float*)alloc((size_t)G_GRAPHS * 32 * 4);

    float* hstat1 = stats + 1024;
    float* hstat2 = stats + 1024 + 128;

    hipMemsetAsync(d_ws, 0, zero_bytes, stream);

    k_deg<<<3125, 256, 0, stream>>>(dstp, cnt);
    k_bsum<<<NB_SCAN, 256, 0, stream>>>(cnt, bsum, dis);
    k_bscan<<<1, 256, 0, stream>>>(bsum, boff, row_ptr);
    k_rowptr<<<NB_SCAN, 256, 0, stream>>>(cnt, boff, row_ptr);
    k_scatter<<<3125, 256, 0, stream>>>(srcp, dstp, row_ptr, cursor, csr);
    k_proj<<<12500, 256, 0, stream>>>(x, proj_W, proj_b, BA);

    // 3-buffer rotation: per layer A holds h_in.
    float* A = BA; float* B = BB; float* C = BC;
    for (int l = 0; l < 4; l++) {
        const float* W0 = conv_W + (size_t)(l * 2 + 0) * 4096;
        const float* W1c = conv_W + (size_t)(l * 2 + 1) * 4096;
        float* st0 = stats + (size_t)(l * 2 + 0) * 128;
        float* st1 = stats + (size_t)(l * 2 + 1) * 128;
        k_gemm<0><<<782, 256, 0, stream>>>(A, W0, dis, nullptr, B);
        k_agg<<<2048, 256, 0, stream>>>(B, row_ptr, csr, dis, C, st0);
        k_fin<<<1, 64, 0, stream>>>(st0, bn_g + (l * 2) * 64, bn_b + (l * 2) * 64, coef);
        k_gemm<1><<<782, 256, 0, stream>>>(C, W1c, dis, coef, B);
        k_agg<<<2048, 256, 0, stream>>>(B, row_ptr, csr, dis, C, st1);
        k_fin<<<1, 64, 0, stream>>>(st1, bn_g + (l * 2 + 1) * 64, bn_b + (l * 2 + 1) * 64, coef);
        k_res<<<3125, 256, 0, stream>>>(C, A, coef, B);
        float* t0 = A; A = B; B = C; C = t0;  // new h in (old) B
    }

    k_pool<<<256, 256, 0, stream>>>(A, batch, pmean, pmax);
    k_head1<<<32, 256, 0, stream>>>(pmean, pmax, lin1_W, z1buf, hstat1);
    k_head2<<<32, 256, 0, stream>>>(z1buf, lin2_W, hstat1, bnf1_g, bnf1_b, z2buf, hstat2);
    k_head3<<<1, 256, 0, stream>>>(z2buf, lin3_W, lin3_b, hstat2, bnf2_g, bnf2_b, (float*)d_out);
}